// Round 2
// baseline (331.521 us; speedup 1.0000x reference)
//
#include <hip/hip_runtime.h>

#define NN 64
#define CC 128
#define TT 2048
#define SS 9
#define PAD 4
#define EPSF 1e-5f
#define TCHUNK 256           // t columns per block (64 lanes x 4)
#define NCHUNK (TT / TCHUNK) // 8

// 4-float vector with 4-byte alignment: lets the compiler emit a legal
// (possibly split) vector load for the sh-shifted, 4B-aligned addresses.
typedef float f4u __attribute__((ext_vector_type(4), aligned(4)));

// PHASE 0: conv -> per-channel sum/sumsq (atomics into stats[0..C), stats[C..2C))
// PHASE 1: conv -> normalize (from stats) -> ReLU -> out
template <int PHASE>
__global__ __launch_bounds__(256) void conv_fused_kernel(
    const float* __restrict__ x, const float* __restrict__ cw,
    const float* __restrict__ gamma, const float* __restrict__ beta,
    float* __restrict__ stats, float* __restrict__ out)
{
    const int n    = blockIdx.y;
    const int t0   = blockIdx.x * TCHUNK;
    const int wid  = threadIdx.x >> 6;   // wave id 0..3
    const int lane = threadIdx.x & 63;
    const int tb   = t0 + lane * 4;      // this thread's 4 output t's
    const int W    = wid * 32;           // wave's output-channel base

    const float* __restrict__ xn = x + (size_t)n * CC * TT;

    const bool firstChunk = (t0 == 0);
    const bool lastChunk  = (t0 == TT - TCHUNK);

    const float inv_cnt = 1.0f / (float)(NN * TT);

    f4u ring[9];   // sliding window of source-channel values, 4 t's each

    // c2 = W - 4 + i ; output c = c2 - 4 ready for i >= 8
#pragma unroll
    for (int i = 0; i < 40; ++i) {
        const int c2 = W - 4 + i;
        f4u v = {0.f, 0.f, 0.f, 0.f};
        if (c2 >= 0 && c2 < CC) {                 // wave-uniform branch
            const int sh = (c2 % SS) - PAD;       // wave-uniform
            const bool edge = (firstChunk && sh > 0) || (lastChunk && sh < 0);
            const float* p = xn + (size_t)c2 * TT + (tb - sh);
            if (!edge) {
                v = *reinterpret_cast<const f4u*>(p);
            } else {
#pragma unroll
                for (int k = 0; k < 4; ++k) {
                    const int tt = tb + k - sh;
                    float val = 0.f;
                    if (tt >= 0 && tt < TT) val = xn[(size_t)c2 * TT + tt];
                    v[k] = val;
                }
            }
        }
        ring[i % 9] = v;

        if (i >= 8) {
            const int c = c2 - 4;                 // output channel (wave-uniform)
            const float* wrow = cw + c * SS;
            float a0 = 0.f, a1 = 0.f, a2 = 0.f, a3 = 0.f;
#pragma unroll
            for (int s = 0; s < SS; ++s) {
                const float w = wrow[s];          // uniform -> broadcast load
                const f4u t = ring[(i - 8 + s) % 9];
                a0 = fmaf(w, t[0], a0);
                a1 = fmaf(w, t[1], a1);
                a2 = fmaf(w, t[2], a2);
                a3 = fmaf(w, t[3], a3);
            }

            if (PHASE == 0) {
                float s1 = (a0 + a1) + (a2 + a3);
                float s2 = fmaf(a0, a0, fmaf(a1, a1, fmaf(a2, a2, a3 * a3)));
#pragma unroll
                for (int off = 32; off > 0; off >>= 1) {
                    s1 += __shfl_down(s1, off, 64);
                    s2 += __shfl_down(s2, off, 64);
                }
                if (lane == 0) {
                    atomicAdd(&stats[c], s1);
                    atomicAdd(&stats[CC + c], s2);
                }
            } else {
                const float mean = stats[c] * inv_cnt;
                const float var  = stats[CC + c] * inv_cnt - mean * mean;
                const float inv  = rsqrtf(var + EPSF);
                const float g = gamma[c] * inv;
                const float b = beta[c] - mean * g;
                float4 r;
                r.x = fmaf(a0, g, b); r.y = fmaf(a1, g, b);
                r.z = fmaf(a2, g, b); r.w = fmaf(a3, g, b);
                r.x = r.x > 0.f ? r.x : 0.f;
                r.y = r.y > 0.f ? r.y : 0.f;
                r.z = r.z > 0.f ? r.z : 0.f;
                r.w = r.w > 0.f ? r.w : 0.f;
                *reinterpret_cast<float4*>(out + ((size_t)n * CC + c) * TT + tb) = r;
            }
        }
    }
}

extern "C" void kernel_launch(void* const* d_in, const int* in_sizes, int n_in,
                              void* d_out, int out_size, void* d_ws, size_t ws_size,
                              hipStream_t stream)
{
    const float* x     = (const float*)d_in[0];
    const float* cw    = (const float*)d_in[1];
    const float* gamma = (const float*)d_in[2];
    const float* beta  = (const float*)d_in[3];
    float* out   = (float*)d_out;
    float* stats = (float*)d_ws;   // [0..C): sum, [C..2C): sumsq

    hipMemsetAsync(stats, 0, 2 * CC * sizeof(float), stream);
    dim3 grid(NCHUNK, NN);
    conv_fused_kernel<0><<<grid, 256, 0, stream>>>(x, cw, gamma, beta, stats, out);
    conv_fused_kernel<1><<<grid, 256, 0, stream>>>(x, cw, gamma, beta, stats, out);
}

// Round 3
// 206.789 us; speedup vs baseline: 1.6032x; 1.6032x over previous
//
#include <hip/hip_runtime.h>

#define NN 64
#define CC 128
#define TT 2048
#define SS 9
#define PAD 4
#define EPSF 1e-5f
#define TL 64                 // t columns per block
#define ROWS (CC + 2 * PAD)   // 136 rows: 4 zero + 128 data + 4 zero
#define STRIDE (TL + 1)       // 65: +1 pad -> 2-way-free bank access

// PHASE 0: conv -> per-thread (fixed c) sum/sumsq -> atomics into stats
// PHASE 1: conv -> normalize(stats) -> ReLU -> LDS transpose -> coalesced store
template <int PHASE>
__global__ __launch_bounds__(256, 4) void s2conv_kernel(
    const float* __restrict__ x, const float* __restrict__ cw,
    const float* __restrict__ gamma, const float* __restrict__ beta,
    float* __restrict__ stats, float* __restrict__ out)
{
    __shared__ float ls[ROWS * STRIDE];   // 35.4 KB

    const int n    = blockIdx.y;
    const int t0   = blockIdx.x * TL;
    const int tid  = threadIdx.x;
    const int lane = tid & 63;
    const int wrow = tid >> 6;            // 0..3 (wave id)
    const float* __restrict__ xn = x + (size_t)n * CC * TT;

    // ---- stage shifted tile: ls[c2+4][j] = xs[n, c2, t0+j], zero-padded ----
#pragma unroll
    for (int rr = 0; rr < ROWS; rr += 4) {
        const int r  = rr + wrow;         // wave-uniform row
        const int c2 = r - PAD;
        float v = 0.f;
        if (c2 >= 0 && c2 < CC) {         // wave-uniform
            const int sh = (c2 % SS) - PAD;
            const int t  = t0 + lane - sh;
            if (t >= 0 && t < TT) v = xn[c2 * TT + t];
        }
        ls[r * STRIDE + lane] = v;
    }

    // ---- per-thread params (before barrier; independent of LDS) ----
    const int c  = tid & (CC - 1);        // fixed output channel
    const int jb = (tid >> 7) * (TL / 2); // 0 or 32
    float wv[SS];
#pragma unroll
    for (int s = 0; s < SS; ++s) wv[s] = cw[c * SS + s];

    float g = 0.f, b = 0.f;
    if (PHASE == 1) {
        const float inv_cnt = 1.0f / (float)(NN * TT);
        const float mean = stats[c] * inv_cnt;
        const float var  = stats[CC + c] * inv_cnt - mean * mean;
        const float inv  = rsqrtf(var + EPSF);
        g = gamma[c] * inv;
        b = beta[c] - mean * g;
    }

    __syncthreads();

    // ---- conv: 32 independent outputs per thread, rows c..c+8 ----
    const int base = c * STRIDE + jb;
    float s1 = 0.f, s2 = 0.f;
    float res[TL / 2];
#pragma unroll
    for (int j = 0; j < TL / 2; ++j) {
        float acc = 0.f;
#pragma unroll
        for (int s = 0; s < SS; ++s)
            acc = fmaf(wv[s], ls[base + s * STRIDE + j], acc);
        if (PHASE == 0) {
            s1 += acc;
            s2 = fmaf(acc, acc, s2);
        } else {
            const float v = fmaf(acc, g, b);
            res[j] = v > 0.f ? v : 0.f;
        }
    }

    if (PHASE == 0) {
        // pair (tid, tid+128) share c: combine via LDS, one atomic pair per c
        __syncthreads();
        ls[tid]       = s1;
        ls[256 + tid] = s2;
        __syncthreads();
        if (tid < CC) {
            atomicAdd(&stats[tid],      ls[tid]       + ls[tid + 128]);
            atomicAdd(&stats[CC + tid], ls[256 + tid] + ls[256 + tid + 128]);
        }
    } else {
        // transpose through LDS for coalesced stores
        __syncthreads();
#pragma unroll
        for (int j = 0; j < TL / 2; ++j)
            ls[c * STRIDE + jb + j] = res[j];
        __syncthreads();
        float* __restrict__ on = out + (size_t)n * CC * TT + t0;
#pragma unroll
        for (int rr = 0; rr < CC; rr += 4) {
            const int r = rr + wrow;      // wave-uniform row = channel
            on[(size_t)r * TT + lane] = ls[r * STRIDE + lane];
        }
    }
}

extern "C" void kernel_launch(void* const* d_in, const int* in_sizes, int n_in,
                              void* d_out, int out_size, void* d_ws, size_t ws_size,
                              hipStream_t stream)
{
    const float* x     = (const float*)d_in[0];
    const float* cw    = (const float*)d_in[1];
    const float* gamma = (const float*)d_in[2];
    const float* beta  = (const float*)d_in[3];
    float* out   = (float*)d_out;
    float* stats = (float*)d_ws;   // [0..C): sum, [C..2C): sumsq

    hipMemsetAsync(stats, 0, 2 * CC * sizeof(float), stream);
    dim3 grid(TT / TL, NN);        // 32 x 64 = 2048 blocks
    s2conv_kernel<0><<<grid, 256, 0, stream>>>(x, cw, gamma, beta, stats, out);
    s2conv_kernel<1><<<grid, 256, 0, stream>>>(x, cw, gamma, beta, stats, out);
}

// Round 4
// 160.703 us; speedup vs baseline: 2.0629x; 1.2868x over previous
//
#include <hip/hip_runtime.h>

#define NN 64
#define CC 128
#define TT 2048
#define SS 9
#define PAD 4
#define EPSF 1e-5f
#define TL 32                 // t columns per block
#define ROWS (CC + 2 * PAD)   // 136 staged rows
#define STRIDE (TL + 1)       // 33: odd -> conflict-free c-per-lane reads
#define NBUCKET 16

// K1: stage shifted tile -> conv -> (a) raw conv to out (LDS transpose,
// coalesced), (b) per-thread sum/sumsq -> bucketed global atomics.
__global__ __launch_bounds__(256, 8) void conv_store_stats(
    const float* __restrict__ x, const float* __restrict__ cw,
    float* __restrict__ buckets, float* __restrict__ out, int bmask)
{
    __shared__ float ls[ROWS * STRIDE];   // 17.9 KB -> 8 blocks/CU

    const int n     = blockIdx.y;
    const int t0    = blockIdx.x * TL;
    const int tid   = threadIdx.x;
    const int lane  = tid & 63;
    const int wid   = tid >> 6;
    const int col   = lane & 31;
    const int rhalf = lane >> 5;          // two 32-lane rows per wave instr
    const float* __restrict__ xn = x + (size_t)n * CC * TT;

    // ---- stage: ls[c2+4][j] = xs[n, c2, t0+j] (pre-shifted, zero-padded) ----
#pragma unroll
    for (int i = 0; i < 17; ++i) {        // 34 rows per wave, 2 per iter
        const int r  = wid * 34 + 2 * i + rhalf;
        const int c2 = r - PAD;
        float v = 0.f;
        if (c2 >= 0 && c2 < CC) {
            const int sh = (c2 % SS) - PAD;
            const int t  = t0 + col - sh;
            if (t >= 0 && t < TT) v = xn[c2 * TT + t];
        }
        ls[r * STRIDE + col] = v;
    }

    const int c  = tid & (CC - 1);        // fixed output channel per thread
    const int jb = (tid >> 7) * (TL / 2); // 0 or 16
    float wv[SS];
#pragma unroll
    for (int s = 0; s < SS; ++s) wv[s] = cw[c * SS + s];

    __syncthreads();

    // ---- conv: rows c..c+8, conflict-free (STRIDE odd, c = lane) ----
    const int base = c * STRIDE + jb;
    float res[TL / 2];
    float s1 = 0.f, s2 = 0.f;
#pragma unroll
    for (int j = 0; j < TL / 2; ++j) {
        float acc = 0.f;
#pragma unroll
        for (int s = 0; s < SS; ++s)
            acc = fmaf(wv[s], ls[base + s * STRIDE + j], acc);
        res[j] = acc;
        s1 += acc;
        s2 = fmaf(acc, acc, s2);
    }

    // ---- stats: bucketed atomics (lanes hit distinct addresses) ----
    {
        float* bs = buckets + ((blockIdx.x + blockIdx.y) & bmask) * 2 * CC;
        atomicAdd(&bs[c], s1);
        atomicAdd(&bs[CC + c], s2);
    }

    // ---- raw conv -> out, coalesced via LDS transpose ----
    __syncthreads();                      // conv reads done; safe to overwrite
#pragma unroll
    for (int j = 0; j < TL / 2; ++j)
        ls[c * STRIDE + jb + j] = res[j];
    __syncthreads();
    float* __restrict__ on = out + (size_t)n * CC * TT + t0;
#pragma unroll
    for (int i = 0; i < 16; ++i) {        // 32 rows per wave, 2 per iter
        const int r = wid * 32 + 2 * i + rhalf;
        on[(size_t)r * TT + col] = ls[r * STRIDE + col];
    }
}

// K1b: fold buckets -> per-channel g = gamma*rsqrt(var+eps), b = beta - mean*g
__global__ void fold_stats(const float* __restrict__ buckets,
                           const float* __restrict__ gamma,
                           const float* __restrict__ beta,
                           float* __restrict__ gb, int nb)
{
    const int c = threadIdx.x;            // 128 threads
    float s1 = 0.f, s2 = 0.f;
    for (int k = 0; k < nb; ++k) {
        s1 += buckets[k * 2 * CC + c];
        s2 += buckets[k * 2 * CC + CC + c];
    }
    const float inv_cnt = 1.0f / (float)(NN * TT);
    const float mean = s1 * inv_cnt;
    const float var  = s2 * inv_cnt - mean * mean;
    const float inv  = rsqrtf(var + EPSF);
    const float g = gamma[c] * inv;
    gb[c]      = g;
    gb[CC + c] = beta[c] - mean * g;
}

// K2: in-place normalize + ReLU, pure float4 streaming.
__global__ __launch_bounds__(256, 8) void norm_relu(
    const float* __restrict__ gb, float* __restrict__ out)
{
    const int gtid = blockIdx.x * 256 + threadIdx.x;      // 524288 threads
    const int c = (gtid >> 9) & (CC - 1);  // 512 float4 per (n,c) row; constant
                                           // across the k-loop (stride>>9 ≡ 0 mod 128)
    const float g = gb[c], b = gb[CC + c];
    float4* __restrict__ o4 = (float4*)out;
#pragma unroll
    for (int k = 0; k < 8; ++k) {
        const size_t i = (size_t)gtid + (size_t)k * 524288;
        float4 v = o4[i];
        v.x = fmaf(v.x, g, b); v.y = fmaf(v.y, g, b);
        v.z = fmaf(v.z, g, b); v.w = fmaf(v.w, g, b);
        v.x = v.x > 0.f ? v.x : 0.f;
        v.y = v.y > 0.f ? v.y : 0.f;
        v.z = v.z > 0.f ? v.z : 0.f;
        v.w = v.w > 0.f ? v.w : 0.f;
        o4[i] = v;
    }
}

extern "C" void kernel_launch(void* const* d_in, const int* in_sizes, int n_in,
                              void* d_out, int out_size, void* d_ws, size_t ws_size,
                              hipStream_t stream)
{
    const float* x     = (const float*)d_in[0];
    const float* cw    = (const float*)d_in[1];
    const float* gamma = (const float*)d_in[2];
    const float* beta  = (const float*)d_in[3];
    float* out = (float*)d_out;

    // ws: [nb][2][CC] bucket partials, then [2][CC] folded g/b
    const int nb = (ws_size >= (size_t)(NBUCKET * 2 * CC + 2 * CC) * 4)
                       ? NBUCKET : 1;
    float* buckets = (float*)d_ws;
    float* gb      = buckets + nb * 2 * CC;

    hipMemsetAsync(buckets, 0, (size_t)nb * 2 * CC * 4, stream);
    dim3 grid1(TT / TL, NN);              // 64 x 64 = 4096 blocks
    conv_store_stats<<<grid1, 256, 0, stream>>>(x, cw, buckets, out, nb - 1);
    fold_stats<<<1, CC, 0, stream>>>(buckets, gamma, beta, gb, nb);
    norm_relu<<<(NN * CC * TT / 4) / (256 * 8), 256, 0, stream>>>(gb, out);
}